// Round 10
// baseline (320.240 us; speedup 1.0000x reference)
//
#include <hip/hip_runtime.h>
#include <hip/hip_bf16.h>
#include <math.h>
#include <stdint.h>

#define BATCH 2
#define SEQ   2048
#define DMODEL 1024
#define NHEAD 16
#define HDIM  64
#define NROWS (BATCH*SEQ)          // 4096
#define EPS   1e-6f
#define QSCALE 0.1803368801111204f // 0.125 * log2(e): softmax in exp2 domain

typedef float f32x4 __attribute__((ext_vector_type(4)));
typedef short s16x8 __attribute__((ext_vector_type(8)));
typedef unsigned int u32x4 __attribute__((ext_vector_type(4)));

// ws layout (ushort units):
//  xq @ 0            (4194304)   -> reused as ab (attention out) after projections
//  xk @ 4194304
//  xv @ 8388608
//  wq @ 12582912     (1048576 each)
//  wk @ 13631488
//  wv @ 14680064
//  wo @ 15728640
//  qb @ 16777216     [B,H,S,64] bf16, pre-scaled by QSCALE
//  kb @ 20971520     [B,H,S,64] bf16
//  vt @ 25165824     [B,H,64,S] bf16 (V transposed)
//  cmask @ 29360128  (1 MB): [B][32 kblocks][S] uint64 bitmask
//  msum  @ 29884416  (128 B): [B][16 qb128] uint32, bit kb = "has masked"
#define OFF_XQ 0
#define OFF_XK 4194304
#define OFF_XV 8388608
#define OFF_WQ 12582912
#define OFF_WK 13631488
#define OFF_WV 14680064
#define OFF_WO 15728640
#define OFF_QB 16777216
#define OFF_KB 20971520
#define OFF_VT 25165824
#define OFF_CM 29360128
#define OFF_MS 29884416

__device__ __forceinline__ unsigned short f2bf(float x) {
    unsigned int u = __builtin_bit_cast(unsigned int, x);
    u += 0x7fff + ((u >> 16) & 1);            // round-to-nearest-even
    return (unsigned short)(u >> 16);
}

__device__ __forceinline__ void gl_lds16(const void* g, void* l) {
    __builtin_amdgcn_global_load_lds(
        (const __attribute__((address_space(1))) unsigned int*)g,
        (__attribute__((address_space(3))) unsigned int*)(unsigned int)(unsigned long long)l,
        16, 0, 0);
}

// ---------------------------------------------------------------------------
// fused fp32 -> bf16 convert of query/key/value + 4 weight matrices
// (also zero-inits the mask summary words for the following dispatch)
// ---------------------------------------------------------------------------
__global__ __launch_bounds__(256) void conv_all_kernel(
    const float* __restrict__ q, const float* __restrict__ k, const float* __restrict__ v,
    const float* __restrict__ wq, const float* __restrict__ wk, const float* __restrict__ wv,
    const float* __restrict__ wo, unsigned short* __restrict__ ws)
{
    if (blockIdx.x == 0 && threadIdx.x < 32)
        ((unsigned int*)(ws + OFF_MS))[threadIdx.x] = 0;
    size_t t = ((size_t)blockIdx.x * 256 + threadIdx.x) * 4;
    const float* src; unsigned short* dst; size_t off;
    if (t < 4194304)       { src = q;  dst = ws + OFF_XQ; off = t; }
    else if (t < 8388608)  { src = k;  dst = ws + OFF_XK; off = t - 4194304; }
    else if (t < 12582912) { src = v;  dst = ws + OFF_XV; off = t - 8388608; }
    else if (t < 13631488) { src = wq; dst = ws + OFF_WQ; off = t - 12582912; }
    else if (t < 14680064) { src = wk; dst = ws + OFF_WK; off = t - 13631488; }
    else if (t < 15728640) { src = wv; dst = ws + OFF_WV; off = t - 14680064; }
    else                   { src = wo; dst = ws + OFF_WO; off = t - 15728640; }
    float4 x = *(const float4*)&src[off];
    ushort4 o;
    o.x = f2bf(x.x); o.y = f2bf(x.y); o.z = f2bf(x.z); o.w = f2bf(x.w);
    *(ushort4*)&dst[off] = o;
}

// ---------------------------------------------------------------------------
// Shared GEMM tile body: C[128x128] += A[r0..] * W[c0..]^T, bf16 MFMA.
// A,W row-major bf16 with K stride 1024. Per-wave 64x64 = 4x4 C-frags.
// LDS rows (128 B) are XOR-ROTATED by row index: phys 16B-group p of row r
// holds logical group (p - r) & 7 (rotation folded into the GLOBAL source
// address, since global_load_lds's LDS side is fixed base + lane*16).
// Fragment rows step by 16 (= 0 mod 8) so the rotation group
// ((ks*4+quad+row)&7) is independent of mt/nt -> hoisted base offsets +
// compile-time mt*2048 immediates (same algebra verified in attn R17).
// ---------------------------------------------------------------------------
__device__ __forceinline__ void gemm_body(
    const unsigned short* A, const unsigned short* W, int r0, int c0,
    unsigned short* As, unsigned short* Bs, f32x4 acc[4][4])
{
    const int tid  = threadIdx.x;
    const int wave = tid >> 6, lane = tid & 63;
    const int quad = lane >> 4, l15 = lane & 15;
    const int wr = wave >> 1, wc = wave & 1;
    // hoisted fragment base byte-offsets (group indep. of mt/nt)
    const int aBase0 = (wr*64 + l15)*128 + ((    quad + l15) & 7)*16;
    const int aBase1 = (wr*64 + l15)*128 + ((4 + quad + l15) & 7)*16;
    const int bBase0 = (wc*64 + l15)*128 + ((    quad + l15) & 7)*16;
    const int bBase1 = (wc*64 + l15)*128 + ((4 + quad + l15) & 7)*16;
    for (int k0 = 0; k0 < DMODEL; k0 += 64) {
        __syncthreads();
        #pragma unroll
        for (int r = 0; r < 4; r++) {
            int f   = r * 4096 + tid * 16;    // byte offset in 16KB tile
            int row = f >> 7;                 // tile row 0..127
            int g   = (((f >> 4) & 7) - row) & 7;   // logical group at this slot
            gl_lds16((const char*)A + (size_t)(r0 + row) * 2048 + k0 * 2 + g * 16,
                     (char*)As + r * 4096 + wave * 1024);
            gl_lds16((const char*)W + (size_t)(c0 + row) * 2048 + k0 * 2 + g * 16,
                     (char*)Bs + r * 4096 + wave * 1024);
        }
        __syncthreads();
        #pragma unroll
        for (int ks = 0; ks < 2; ks++) {
            const int aB = ks ? aBase1 : aBase0;
            const int bB = ks ? bBase1 : bBase0;
            s16x8 a[4], b[4];
            #pragma unroll
            for (int mt = 0; mt < 4; mt++)
                a[mt] = *(const s16x8*)((const char*)As + aB + mt*2048);
            #pragma unroll
            for (int nt = 0; nt < 4; nt++)
                b[nt] = *(const s16x8*)((const char*)Bs + bB + nt*2048);
            #pragma unroll
            for (int mt = 0; mt < 4; mt++)
                #pragma unroll
                for (int nt = 0; nt < 4; nt++)
                    acc[mt][nt] = __builtin_amdgcn_mfma_f32_16x16x32_bf16(a[mt], b[nt], acc[mt][nt], 0, 0, 0);
        }
    }
}

// ---------------------------------------------------------------------------
// QKV projections + fused mask compression.
// z=0 -> q (scaled, [B,H,S,d]), z=1 -> k ([B,H,S,d]),
// z=2 -> V^T computed DIRECTLY as Wv * X^T (operand swap, coalesced stores),
// z=3 -> mask compress (256 blocks, one wave per (b,kb,s) row, grid-stride
//        x128): lane reads mask[b][s][kb*64+lane] (coalesced 256B/wave),
//        __ballot assembles the 64-bit mask. Runs concurrently with the
//        GEMM slices -- its HBM reads hide under their MFMA work. msum was
//        zero-inited by conv (previous dispatch), and attn (next dispatch)
//        only starts after this one completes.
// ---------------------------------------------------------------------------
__global__ __launch_bounds__(256) void qkv_gemm_kernel(
    unsigned short* __restrict__ ws,
    const float* __restrict__ bq, const float* __restrict__ bk, const float* __restrict__ bv,
    const int* __restrict__ mask)
{
    const int z = blockIdx.z;
    if (z == 3) {
        // ---- mask compression slice ----
        unsigned long long* cm = (unsigned long long*)(ws + OFF_CM);
        unsigned int* msum = (unsigned int*)(ws + OFF_MS);
        const int lane = threadIdx.x & 63;
        const int wv = threadIdx.x >> 6;                     // wave in block
        const int bid = blockIdx.y * 32 + blockIdx.x;        // 0..255
        const int wbase = (bid * 4 + wv) * 128;              // 128 rows/wave
        for (int i = 0; i < 128; i++) {
            int w = wbase + i;                   // row id [0, 131072)
            int s  = w & 2047;
            int kb = (w >> 11) & 31;
            int b  = w >> 16;
            int m = mask[((size_t)b * SEQ + s) * SEQ + kb * 64 + lane];
            unsigned long long bits = __ballot(m != 0);
            if (lane == 0) {
                cm[((size_t)b * 32 + kb) * SEQ + s] = bits;
                if (bits != ~0ull)
                    atomicOr(&msum[(b << 4) | (s >> 7)], 1u << kb);
            }
        }
        return;
    }

    __shared__ __align__(16) unsigned short As[8192];
    __shared__ __align__(16) unsigned short Bs[8192];
    const unsigned short *A, *W;
    int r0, c0;
    if (z != 2) {
        A = ws + (size_t)z * 4194304;            // xq/xk
        W = ws + OFF_WQ + (size_t)z * 1048576;
        r0 = blockIdx.x * 128; c0 = blockIdx.y * 128;
    } else {
        A = ws + OFF_WV;                         // rows = output features
        W = ws + OFF_XV;                         // "cols" = seq rows
        r0 = blockIdx.y * 128; c0 = blockIdx.x * 128;
    }
    const float* bias = (z == 0) ? bq : (z == 1 ? bk : bv);
    unsigned short* outp = ws + OFF_QB + (size_t)z * 4194304;      // qb/kb/vt
    const float scale = (z == 0) ? QSCALE : 1.0f;

    f32x4 acc[4][4] = {};
    gemm_body(A, W, r0, c0, As, Bs, acc);

    const int lane = threadIdx.x & 63, wave = threadIdx.x >> 6;
    const int quad = lane >> 4, l15 = lane & 15;
    const int wr = wave >> 1, wc = wave & 1;
    if (z != 2) {
        float bias_v[4];
        #pragma unroll
        for (int nt = 0; nt < 4; nt++) bias_v[nt] = bias[c0 + wc*64 + nt*16 + l15];
        #pragma unroll
        for (int mt = 0; mt < 4; mt++) {
            #pragma unroll
            for (int nt = 0; nt < 4; nt++) {
                int c = c0 + wc*64 + nt*16 + l15;
                int hh = c >> 6, dd = c & 63;
                #pragma unroll
                for (int reg = 0; reg < 4; reg++) {
                    int r = r0 + wr*64 + mt*16 + quad*4 + reg;
                    int bb = r >> 11, ss = r & (SEQ - 1);
                    float val = (acc[mt][nt][reg] + bias_v[nt]) * scale;
                    outp[(((size_t)(bb*NHEAD + hh)) * SEQ + ss) * HDIM + dd] = f2bf(val);
                }
            }
        }
    } else {
        #pragma unroll
        for (int mt = 0; mt < 4; mt++) {
            #pragma unroll
            for (int reg = 0; reg < 4; reg++) {
                int f = r0 + wr*64 + mt*16 + quad*4 + reg;   // feature
                int hh = f >> 6, dd = f & 63;
                float bfv = bias[f];
                #pragma unroll
                for (int nt = 0; nt < 4; nt++) {
                    int r = c0 + wc*64 + nt*16 + l15;        // seq row
                    int bb = r >> 11, ss = r & (SEQ - 1);
                    outp[(((size_t)(bb*NHEAD + hh)) * HDIM + dd) * SEQ + ss] =
                        f2bf(acc[mt][nt][reg] + bfv);
                }
            }
        }
    }
}

// ---------------------------------------------------------------------------
// Out projection: out = ab @ Wo^T + bo + residual  (fp32 out)
// ---------------------------------------------------------------------------
__global__ __launch_bounds__(256) void oproj_gemm_kernel(
    const unsigned short* __restrict__ ws, const float* __restrict__ bo,
    const float* __restrict__ resid, float* __restrict__ outf)
{
    __shared__ __align__(16) unsigned short As[8192];
    __shared__ __align__(16) unsigned short Bs[8192];
    const unsigned short* A = ws + OFF_XQ;      // ab lives where xq was
    const unsigned short* W = ws + OFF_WO;
    const int r0 = blockIdx.x * 128, c0 = blockIdx.y * 128;

    f32x4 acc[4][4] = {};
    gemm_body(A, W, r0, c0, (unsigned short*)As, (unsigned short*)Bs, acc);

    const int lane = threadIdx.x & 63, wave = threadIdx.x >> 6;
    const int quad = lane >> 4, l15 = lane & 15;
    const int wr = wave >> 1, wc = wave & 1;
    #pragma unroll
    for (int mt = 0; mt < 4; mt++) {
        #pragma unroll
        for (int nt = 0; nt < 4; nt++) {
            int c = c0 + wc*64 + nt*16 + l15;
            float bv = bo[c];
            #pragma unroll
            for (int reg = 0; reg < 4; reg++) {
                int r = r0 + wr*64 + mt*16 + quad*4 + reg;
                size_t idx = (size_t)r * DMODEL + c;
                outf[idx] = acc[mt][nt][reg] + bv + resid[idx];
            }
        }
    }
}

// ---------------------------------------------------------------------------
// Flash attention, bf16 MFMA, static softmax. Reverted to the proven R14
// structure (best measured: 57.6us): 512 thr, 8 waves x 16 q-rows, swapped
// QK^T, key-permuted K staging, P in registers via v_perm_b32, l via
// ones-column MFMA, 128-key mega-chunks (two 8KB half-buffers per operand
// per dbuf slot, one barrier per 128 keys), 0 bank conflicts. Keeps R17's
// verified fbase offset hoist (rows step by 16 -> rotation group indep. of
// kt/nt; saves the 16-VGPR koff/voff arrays). R15 stagger (neutral) and
// R16/R17 key-split (occupancy theory falsified: 1024-thr barrier couples
// 16 waves, HW granted 1 block/CU) are both dropped.
// ---------------------------------------------------------------------------
__global__ __launch_bounds__(512) void attn_mfma_kernel(
    const unsigned short* __restrict__ ws,
    const unsigned long long* __restrict__ cmask,
    const unsigned int* __restrict__ msum,
    unsigned short* __restrict__ ab)
{
    const int tid  = threadIdx.x;
    const int wave = tid >> 6, lane = tid & 63;
    const int quad = lane >> 4, l15 = lane & 15;
    const int h = blockIdx.y, b = blockIdx.z;
    const int qw = blockIdx.x * 128 + wave * 16;

    const char* qh = (const char*)(ws + OFF_QB + ((size_t)(b*NHEAD + h)) * SEQ * HDIM);
    const char* kh = (const char*)(ws + OFF_KB + ((size_t)(b*NHEAD + h)) * SEQ * HDIM);
    const char* vh = (const char*)(ws + OFF_VT + ((size_t)(b*NHEAD + h)) * SEQ * HDIM);

    __shared__ __align__(16) char Ks[2][2][8192]; // [dbuf][64-key half][perm key][d]
    __shared__ __align__(16) char Vs[2][2][8192]; // [dbuf][64-key half][d][key]

    const unsigned int chunkflags = msum[(b << 4) | blockIdx.x];

    // staging: 512 threads x 16B = one 8KB half-buffer per call; LDS row =
    // tid>>3, phys group tid&7 holds logical group ((tid&7)-row)&7 (rotate).
    // K source row is the PERMUTED key a(row): bits [r5][r3 r2][r4][r1 r0].
    const int srow = tid >> 3;
    const int sgrp = ((tid & 7) - srow) & 7;
    const int arow = (srow & 0x23) | ((srow & 0x0C) << 1) | ((srow & 0x10) >> 2);

    #define STAGE(bfi, k0)                                                           \
        do {                                                                         \
            gl_lds16(kh + (size_t)((k0) + arow) * 128 + sgrp * 16,                   \
                     Ks[bfi][0] + wave * 1024);                                      \
            gl_lds16(kh + (size_t)((k0) + 64 + arow) * 128 + sgrp * 16,              \
                     Ks[bfi][1] + wave * 1024);                                      \
            gl_lds16(vh + (size_t)srow * 4096 + (size_t)(k0) * 2 + sgrp * 16,        \
                     Vs[bfi][0] + wave * 1024);                                      \
            gl_lds16(vh + (size_t)srow * 4096 + (size_t)((k0) + 64) * 2 + sgrp * 16, \
                     Vs[bfi][1] + wave * 1024);                                      \
        } while (0)

    s16x8 qa[2];
    #pragma unroll
    for (int ks = 0; ks < 2; ks++)
        qa[ks] = *(const s16x8*)(qh + (size_t)(qw + l15) * 128 + ks*64 + quad*16);

    // fragment base byte-offsets: rows step by 16 (= 0 mod 8) so the
    // rotation group ((ks*4+quad+row)&7) depends only on (quad+l15);
    // kt/nt contribute pure +2048 immediates. (Verified in R17.)
    const int fbaseA = l15*128 + ((    quad + l15) & 7) * 16;   // ks=0
    const int fbaseB = l15*128 + ((4 + quad + l15) & 7) * 16;   // ks=1

    s16x8 onesf;
    {
        short so = (short)0x3F80;  // bf16 1.0
        if (l15 == 0) onesf = (s16x8){so, so, so, so, so, so, so, so};
        else          onesf = (s16x8){0, 0, 0, 0, 0, 0, 0, 0};
    }

    f32x4 o[4], lsum = {0.f, 0.f, 0.f, 0.f};
    #pragma unroll
    for (int nt = 0; nt < 4; nt++) o[nt] = (f32x4){0.f, 0.f, 0.f, 0.f};

    STAGE(0, 0);
    int bf = 0;
    for (int k0 = 0; k0 < SEQ; k0 += 128) {
        __syncthreads();            // vmcnt(0): buf[bf] staged, buf[bf^1] free
        // prefetch next mega-chunk into the other buffer
        if (k0 + 128 < SEQ) STAGE(bf ^ 1, k0 + 128);

        #pragma unroll
        for (int half = 0; half < 2; half++) {
            const char* Kb = Ks[bf][half];
            const char* Vb = Vs[bf][half];
            const int kc = (k0 >> 6) + half;   // 64-key chunk index 0..31
            // --- S^T = K Q^T (exp2-domain, pre-scaled), K as A-operand from
            //     permuted LDS rows; st[kt][reg] = S[key a(kt*16+quad*4+reg)][q=l15]
            f32x4 st[4];
            #pragma unroll
            for (int kt = 0; kt < 4; kt++) {
                s16x8 kf0 = *(const s16x8*)(Kb + fbaseA + kt*2048);
                s16x8 kf1 = *(const s16x8*)(Kb + fbaseB + kt*2048);
                f32x4 z = {0.f, 0.f, 0.f, 0.f};
                st[kt] = __builtin_amdgcn_mfma_f32_16x16x32_bf16(kf0, qa[0], z, 0, 0, 0);
                st[kt] = __builtin_amdgcn_mfma_f32_16x16x32_bf16(kf1, qa[1], st[kt], 0, 0, 0);
            }
            // --- mask: one u64 per lane (q = qw+l15), bit = PERMUTED key index ---
            if (chunkflags & (1u << kc)) {
                unsigned long long cm =
                    cmask[((size_t)b*32 + kc) * SEQ + qw + l15];
                if (cm != ~0ull) {
                    #pragma unroll
                    for (int kt = 0; kt < 4; kt++)
                        #pragma unroll
                        for (int reg = 0; reg < 4; reg++) {
                            int key = (kt >> 1)*32 + quad*8 + (kt & 1)*4 + reg;
                            if (!((cm >> key) & 1)) st[kt][reg] = -1e9f;
                        }
                }
            }
            // --- P = exp2(S), packed to bf16 via v_perm_b32 (byte-extract =
            //     trunc); lane holds keys ks*32+quad*8..+7 = PV A-octets.
            //     l accumulated on the matrix pipe via ones-column MFMA ---
            #pragma unroll
            for (int ks = 0; ks < 2; ks++) {
                unsigned int pb[8];
                #pragma unroll
                for (int j = 0; j < 8; j++) {
                    int kt = 2*ks + (j >> 2), r = j & 3;
                    pb[j] = __builtin_bit_cast(unsigned int, exp2f(st[kt][r]));
                }
                u32x4 pw;
                pw[0] = __builtin_amdgcn_perm(pb[1], pb[0], 0x07060302u);
                pw[1] = __builtin_amdgcn_perm(pb[3], pb[2], 0x07060302u);
                pw[2] = __builtin_amdgcn_perm(pb[5], pb[4], 0x07060302u);
                pw[3] = __builtin_amdgcn_perm(pb[7], pb[6], 0x07060302u);
                s16x8 pa = __builtin_bit_cast(s16x8, pw);
                lsum = __builtin_amdgcn_mfma_f32_16x16x32_bf16(pa, onesf, lsum, 0, 0, 0);
                const int fb = (ks == 0) ? fbaseA : fbaseB;
                #pragma unroll
                for (int nt = 0; nt < 4; nt++) {
                    s16x8 vf = *(const s16x8*)(Vb + fb + nt*2048);
                    o[nt] = __builtin_amdgcn_mfma_f32_16x16x32_bf16(pa, vf, o[nt], 0, 0, 0);
                }
            }
        }
        bf ^= 1;
    }
    #undef STAGE
    // --- epilogue: O / l -> ab [B,S,DMODEL] bf16.
    //     O and lsum share the C layout: row q = quad*4+reg, col = l15
    //     (l valid at col 0 -> lane quad*16 = lane&48) ---
    #pragma unroll
    for (int reg = 0; reg < 4; reg++) {
        float lv = __shfl(lsum[reg], lane & 48);
        float inv = 1.f / lv;
        int sg = qw + quad*4 + reg;
        #pragma unroll
        for (int nt = 0; nt < 4; nt++) {
            size_t idx = ((size_t)b * SEQ + sg) * DMODEL + h*HDIM + nt*16 + l15;
            ab[idx] = f2bf(o[nt][reg] * inv);
        }
    }
}

// ---------------------------------------------------------------------------
// LayerNorm (unbiased std, (std+eps) denominator), in-place on fp32 rows
// ---------------------------------------------------------------------------
__global__ __launch_bounds__(256) void ln_kernel(
    float* __restrict__ x, const float* __restrict__ gamma,
    const float* __restrict__ beta)
{
    const int row = blockIdx.x;
    const int tid = threadIdx.x;
    float4 vals = *(const float4*)&x[(size_t)row * DMODEL + tid * 4];
    float s  = vals.x + vals.y + vals.z + vals.w;
    float ss = vals.x*vals.x + vals.y*vals.y + vals.z*vals.z + vals.w*vals.w;
    #pragma unroll
    for (int off = 32; off > 0; off >>= 1) {
        s  += __shfl_down(s, off);
        ss += __shfl_down(ss, off);
    }
    __shared__ float sbuf[4], ssbuf[4];
    __shared__ float mean_s, inv_s;
    if ((tid & 63) == 0) { sbuf[tid >> 6] = s; ssbuf[tid >> 6] = ss; }
    __syncthreads();
    if (tid == 0) {
        float S1 = 0.f, S2 = 0.f;
        #pragma unroll
        for (int i = 0; i < 4; i++) { S1 += sbuf[i]; S2 += ssbuf[i]; }
        float mean = S1 * (1.0f / DMODEL);
        float var  = (S2 - (float)DMODEL * mean * mean) * (1.0f / (DMODEL - 1));
        float sd   = sqrtf(fmaxf(var, 0.f));
        mean_s = mean;
        inv_s  = 1.f / (sd + EPS);
    }
    __syncthreads();
    float4 g  = *(const float4*)&gamma[tid * 4];
    float4 bt = *(const float4*)&beta[tid * 4];
    float4 o;
    o.x = g.x * (vals.x - mean_s) * inv_s + bt.x;
    o.y = g.y * (vals.y - mean_s) * inv_s + bt.y;
    o.z = g.z * (vals.z - mean_s) * inv_s + bt.z;
    o.w = g.w * (vals.w - mean_s) * inv_s + bt.w;
    *(float4*)&x[(size_t)row * DMODEL + tid * 4] = o;
}

extern "C" void kernel_launch(void* const* d_in, const int* in_sizes, int n_in,
                              void* d_out, int out_size, void* d_ws, size_t ws_size,
                              hipStream_t stream) {
    const float* query = (const float*)d_in[0];
    const float* key   = (const float*)d_in[1];
    const float* value = (const float*)d_in[2];
    const int*   mask  = (const int*)d_in[3];
    const float* Wq = (const float*)d_in[4];  const float* bq = (const float*)d_in[5];
    const float* Wk = (const float*)d_in[6];  const float* bk = (const float*)d_in[7];
    const float* Wv = (const float*)d_in[8];  const float* bv = (const float*)d_in[9];
    const float* Wo = (const float*)d_in[10]; const float* bo = (const float*)d_in[11];
    const float* gamma = (const float*)d_in[12];
    const float* beta  = (const float*)d_in[13];
    float* out = (float*)d_out;

    unsigned short* ws = (unsigned short*)d_ws;
    unsigned long long* cmask = (unsigned long long*)(ws + OFF_CM);
    unsigned int* msum = (unsigned int*)(ws + OFF_MS);

    conv_all_kernel<<<16384, 256, 0, stream>>>(query, key, value, Wq, Wk, Wv, Wo, ws);
    qkv_gemm_kernel<<<dim3(32, 8, 4), 256, 0, stream>>>(ws, bq, bk, bv, mask);
    attn_mfma_kernel<<<dim3(SEQ/128, NHEAD, BATCH), 512, 0, stream>>>(ws, cmask, msum, ws + OFF_XQ);
    oproj_gemm_kernel<<<dim3(32, 8), 256, 0, stream>>>(ws, bo, query, out);
    ln_kernel<<<NROWS, 256, 0, stream>>>(out, gamma, beta);
}

// Round 11
// 272.509 us; speedup vs baseline: 1.1752x; 1.1752x over previous
//
#include <hip/hip_runtime.h>
#include <hip/hip_bf16.h>
#include <math.h>
#include <stdint.h>

#define BATCH 2
#define SEQ   2048
#define DMODEL 1024
#define NHEAD 16
#define HDIM  64
#define NROWS (BATCH*SEQ)          // 4096
#define EPS   1e-6f
#define QSCALE 0.1803368801111204f // 0.125 * log2(e): softmax in exp2 domain

typedef float f32x4 __attribute__((ext_vector_type(4)));
typedef short s16x8 __attribute__((ext_vector_type(8)));
typedef unsigned int u32x4 __attribute__((ext_vector_type(4)));

// ws layout (ushort units):
//  xq @ 0            (4194304)   -> reused as ab (attention out) after projections
//  xk @ 4194304
//  xv @ 8388608
//  wq @ 12582912     (1048576 each)
//  wk @ 13631488
//  wv @ 14680064
//  wo @ 15728640
//  qb @ 16777216     [B,H,S,64] bf16, pre-scaled by QSCALE
//  kb @ 20971520     [B,H,S,64] bf16
//  vt @ 25165824     [B,H,64,S] bf16 (V transposed)
//  cmask @ 29360128  (1 MB): [B][32 kblocks][S] uint64 bitmask
//  msum  @ 29884416  (128 B): [B][16 qb128] uint32, bit kb = "has masked"
#define OFF_XQ 0
#define OFF_XK 4194304
#define OFF_XV 8388608
#define OFF_WQ 12582912
#define OFF_WK 13631488
#define OFF_WV 14680064
#define OFF_WO 15728640
#define OFF_QB 16777216
#define OFF_KB 20971520
#define OFF_VT 25165824
#define OFF_CM 29360128
#define OFF_MS 29884416

__device__ __forceinline__ unsigned short f2bf(float x) {
    unsigned int u = __builtin_bit_cast(unsigned int, x);
    u += 0x7fff + ((u >> 16) & 1);            // round-to-nearest-even
    return (unsigned short)(u >> 16);
}

__device__ __forceinline__ void gl_lds16(const void* g, void* l) {
    __builtin_amdgcn_global_load_lds(
        (const __attribute__((address_space(1))) unsigned int*)g,
        (__attribute__((address_space(3))) unsigned int*)(unsigned int)(unsigned long long)l,
        16, 0, 0);
}

// ---------------------------------------------------------------------------
// fused fp32 -> bf16 convert of query/key/value + 4 weight matrices
// (also zero-inits the mask summary words for the following dispatch)
// ---------------------------------------------------------------------------
__global__ __launch_bounds__(256) void conv_all_kernel(
    const float* __restrict__ q, const float* __restrict__ k, const float* __restrict__ v,
    const float* __restrict__ wq, const float* __restrict__ wk, const float* __restrict__ wv,
    const float* __restrict__ wo, unsigned short* __restrict__ ws)
{
    if (blockIdx.x == 0 && threadIdx.x < 32)
        ((unsigned int*)(ws + OFF_MS))[threadIdx.x] = 0;
    size_t t = ((size_t)blockIdx.x * 256 + threadIdx.x) * 4;
    const float* src; unsigned short* dst; size_t off;
    if (t < 4194304)       { src = q;  dst = ws + OFF_XQ; off = t; }
    else if (t < 8388608)  { src = k;  dst = ws + OFF_XK; off = t - 4194304; }
    else if (t < 12582912) { src = v;  dst = ws + OFF_XV; off = t - 8388608; }
    else if (t < 13631488) { src = wq; dst = ws + OFF_WQ; off = t - 12582912; }
    else if (t < 14680064) { src = wk; dst = ws + OFF_WK; off = t - 13631488; }
    else if (t < 15728640) { src = wv; dst = ws + OFF_WV; off = t - 14680064; }
    else                   { src = wo; dst = ws + OFF_WO; off = t - 15728640; }
    float4 x = *(const float4*)&src[off];
    ushort4 o;
    o.x = f2bf(x.x); o.y = f2bf(x.y); o.z = f2bf(x.z); o.w = f2bf(x.w);
    *(ushort4*)&dst[off] = o;
}

// ---------------------------------------------------------------------------
// mask -> per-(b, kblock, s) 64-bit bitmask + per-(b, qb128) chunk summary.
// R19: back to the SEPARATE kernel (R17 form, best-measured non-attn config;
// R18's fusion into qkv made the serial ballot loop the dispatch's long
// pole, +44us). One wave per row, grid-strided x16 over 2048 blocks: lane
// reads mask[b][s][kb*64+lane] (coalesced 256B/wave), __ballot assembles
// the 64-bit mask in one instruction.
// ---------------------------------------------------------------------------
__global__ __launch_bounds__(256) void mask_compress_kernel(
    const int* __restrict__ mask, unsigned long long* __restrict__ cm,
    unsigned int* __restrict__ msum)
{
    const int lane = threadIdx.x & 63;
    const int wid = (blockIdx.x * 256 + threadIdx.x) >> 6;   // [0, 8192)
    #pragma unroll
    for (int i = 0; i < 16; i++) {
        int w = wid + i * 8192;              // row id [0, 131072)
        int s  = w & 2047;
        int kb = (w >> 11) & 31;
        int b  = w >> 16;
        int m = mask[((size_t)b * SEQ + s) * SEQ + kb * 64 + lane];
        unsigned long long bits = __ballot(m != 0);
        if (lane == 0) {
            cm[((size_t)b * 32 + kb) * SEQ + s] = bits;
            if (bits != ~0ull)
                atomicOr(&msum[(b << 4) | (s >> 7)], 1u << kb);
        }
    }
}

// ---------------------------------------------------------------------------
// Shared GEMM tile body: C[128x128] += A[r0..] * W[c0..]^T, bf16 MFMA.
// A,W row-major bf16 with K stride 1024. Per-wave 64x64 = 4x4 C-frags.
// LDS rows (128 B) are XOR-ROTATED by row index (rotation folded into the
// GLOBAL source address); fragment rows step by 16 (= 0 mod 8) so the
// rotation group is independent of mt/nt -> hoisted base offsets.
// R19: DOUBLE-BUFFERED staging (attn's proven STAGE-ahead pattern): one
// barrier per K-step, next tile's global_load_lds issued before computing
// the current one. The old stage->barrier->compute loop exposed full
// staging latency every K-step -- fatal for oproj's 1-block/CU grid (no
// co-resident-block overlap). LDS 32 -> 64 KB (2 blocks/CU max).
// ---------------------------------------------------------------------------
__device__ __forceinline__ void gemm_body(
    const unsigned short* A, const unsigned short* W, int r0, int c0,
    unsigned short (*As)[8192], unsigned short (*Bs)[8192], f32x4 acc[4][4])
{
    const int tid  = threadIdx.x;
    const int wave = tid >> 6, lane = tid & 63;
    const int quad = lane >> 4, l15 = lane & 15;
    const int wr = wave >> 1, wc = wave & 1;
    // hoisted fragment base byte-offsets (rotation group indep. of mt/nt)
    const int aBase0 = (wr*64 + l15)*128 + ((    quad + l15) & 7)*16;
    const int aBase1 = (wr*64 + l15)*128 + ((4 + quad + l15) & 7)*16;
    const int bBase0 = (wc*64 + l15)*128 + ((    quad + l15) & 7)*16;
    const int bBase1 = (wc*64 + l15)*128 + ((4 + quad + l15) & 7)*16;

    #define GSTAGE(bfi, k0)                                                            \
        do {                                                                           \
            _Pragma("unroll")                                                          \
            for (int r = 0; r < 4; r++) {                                              \
                int f   = r * 4096 + tid * 16;        /* byte offset in 16KB tile */   \
                int row = f >> 7;                     /* tile row 0..127 */            \
                int g   = (((f >> 4) & 7) - row) & 7; /* logical group at this slot */ \
                gl_lds16((const char*)A + (size_t)(r0 + row) * 2048 + (k0) * 2 + g * 16, \
                         (char*)As[bfi] + r * 4096 + wave * 1024);                     \
                gl_lds16((const char*)W + (size_t)(c0 + row) * 2048 + (k0) * 2 + g * 16, \
                         (char*)Bs[bfi] + r * 4096 + wave * 1024);                     \
            }                                                                          \
        } while (0)

    GSTAGE(0, 0);
    int bf = 0;
    for (int k0 = 0; k0 < DMODEL; k0 += 64) {
        __syncthreads();              // vmcnt(0): buf[bf] staged, buf[bf^1] free
        if (k0 + 64 < DMODEL) GSTAGE(bf ^ 1, k0 + 64);
        #pragma unroll
        for (int ks = 0; ks < 2; ks++) {
            const int aB = ks ? aBase1 : aBase0;
            const int bB = ks ? bBase1 : bBase0;
            s16x8 a[4], b[4];
            #pragma unroll
            for (int mt = 0; mt < 4; mt++)
                a[mt] = *(const s16x8*)((const char*)As[bf] + aB + mt*2048);
            #pragma unroll
            for (int nt = 0; nt < 4; nt++)
                b[nt] = *(const s16x8*)((const char*)Bs[bf] + bB + nt*2048);
            #pragma unroll
            for (int mt = 0; mt < 4; mt++)
                #pragma unroll
                for (int nt = 0; nt < 4; nt++)
                    acc[mt][nt] = __builtin_amdgcn_mfma_f32_16x16x32_bf16(a[mt], b[nt], acc[mt][nt], 0, 0, 0);
        }
        bf ^= 1;
    }
    #undef GSTAGE
}

// ---------------------------------------------------------------------------
// QKV projections: z=0 -> q (scaled, [B,H,S,d]), z=1 -> k ([B,H,S,d]),
// z=2 -> V^T computed DIRECTLY as Wv * X^T (operand swap, coalesced stores).
// ---------------------------------------------------------------------------
__global__ __launch_bounds__(256) void qkv_gemm_kernel(
    unsigned short* __restrict__ ws,
    const float* __restrict__ bq, const float* __restrict__ bk, const float* __restrict__ bv)
{
    __shared__ __align__(16) unsigned short As[2][8192];
    __shared__ __align__(16) unsigned short Bs[2][8192];
    const int z = blockIdx.z;
    const unsigned short *A, *W;
    int r0, c0;
    if (z != 2) {
        A = ws + (size_t)z * 4194304;            // xq/xk
        W = ws + OFF_WQ + (size_t)z * 1048576;
        r0 = blockIdx.x * 128; c0 = blockIdx.y * 128;
    } else {
        A = ws + OFF_WV;                         // rows = output features
        W = ws + OFF_XV;                         // "cols" = seq rows
        r0 = blockIdx.y * 128; c0 = blockIdx.x * 128;
    }
    const float* bias = (z == 0) ? bq : (z == 1 ? bk : bv);
    unsigned short* outp = ws + OFF_QB + (size_t)z * 4194304;      // qb/kb/vt
    const float scale = (z == 0) ? QSCALE : 1.0f;

    f32x4 acc[4][4] = {};
    gemm_body(A, W, r0, c0, As, Bs, acc);

    const int lane = threadIdx.x & 63, wave = threadIdx.x >> 6;
    const int quad = lane >> 4, l15 = lane & 15;
    const int wr = wave >> 1, wc = wave & 1;
    if (z != 2) {
        float bias_v[4];
        #pragma unroll
        for (int nt = 0; nt < 4; nt++) bias_v[nt] = bias[c0 + wc*64 + nt*16 + l15];
        #pragma unroll
        for (int mt = 0; mt < 4; mt++) {
            #pragma unroll
            for (int nt = 0; nt < 4; nt++) {
                int c = c0 + wc*64 + nt*16 + l15;
                int hh = c >> 6, dd = c & 63;
                #pragma unroll
                for (int reg = 0; reg < 4; reg++) {
                    int r = r0 + wr*64 + mt*16 + quad*4 + reg;
                    int bb = r >> 11, ss = r & (SEQ - 1);
                    float val = (acc[mt][nt][reg] + bias_v[nt]) * scale;
                    outp[(((size_t)(bb*NHEAD + hh)) * SEQ + ss) * HDIM + dd] = f2bf(val);
                }
            }
        }
    } else {
        #pragma unroll
        for (int mt = 0; mt < 4; mt++) {
            #pragma unroll
            for (int reg = 0; reg < 4; reg++) {
                int f = r0 + wr*64 + mt*16 + quad*4 + reg;   // feature
                int hh = f >> 6, dd = f & 63;
                float bfv = bias[f];
                #pragma unroll
                for (int nt = 0; nt < 4; nt++) {
                    int r = c0 + wc*64 + nt*16 + l15;        // seq row
                    int bb = r >> 11, ss = r & (SEQ - 1);
                    outp[(((size_t)(bb*NHEAD + hh)) * HDIM + dd) * SEQ + ss] =
                        f2bf(acc[mt][nt][reg] + bfv);
                }
            }
        }
    }
}

// ---------------------------------------------------------------------------
// Out projection: out = ab @ Wo^T + bo + residual  (fp32 out)
// ---------------------------------------------------------------------------
__global__ __launch_bounds__(256) void oproj_gemm_kernel(
    const unsigned short* __restrict__ ws, const float* __restrict__ bo,
    const float* __restrict__ resid, float* __restrict__ outf)
{
    __shared__ __align__(16) unsigned short As[2][8192];
    __shared__ __align__(16) unsigned short Bs[2][8192];
    const unsigned short* A = ws + OFF_XQ;      // ab lives where xq was
    const unsigned short* W = ws + OFF_WO;
    const int r0 = blockIdx.x * 128, c0 = blockIdx.y * 128;

    f32x4 acc[4][4] = {};
    gemm_body(A, W, r0, c0, As, Bs, acc);

    const int lane = threadIdx.x & 63, wave = threadIdx.x >> 6;
    const int quad = lane >> 4, l15 = lane & 15;
    const int wr = wave >> 1, wc = wave & 1;
    #pragma unroll
    for (int mt = 0; mt < 4; mt++) {
        #pragma unroll
        for (int nt = 0; nt < 4; nt++) {
            int c = c0 + wc*64 + nt*16 + l15;
            float bv = bo[c];
            #pragma unroll
            for (int reg = 0; reg < 4; reg++) {
                int r = r0 + wr*64 + mt*16 + quad*4 + reg;
                size_t idx = (size_t)r * DMODEL + c;
                outf[idx] = acc[mt][nt][reg] + bv + resid[idx];
            }
        }
    }
}

// ---------------------------------------------------------------------------
// Flash attention, bf16 MFMA, static softmax. The proven R14 structure
// (best measured: 57.6us): 512 thr, 8 waves x 16 q-rows, swapped QK^T,
// key-permuted K staging, P in registers via v_perm_b32, l via ones-column
// MFMA, 128-key mega-chunks (two 8KB half-buffers per operand per dbuf
// slot, one barrier per 128 keys), 0 bank conflicts, fbase offset hoist.
// ---------------------------------------------------------------------------
__global__ __launch_bounds__(512) void attn_mfma_kernel(
    const unsigned short* __restrict__ ws,
    const unsigned long long* __restrict__ cmask,
    const unsigned int* __restrict__ msum,
    unsigned short* __restrict__ ab)
{
    const int tid  = threadIdx.x;
    const int wave = tid >> 6, lane = tid & 63;
    const int quad = lane >> 4, l15 = lane & 15;
    const int h = blockIdx.y, b = blockIdx.z;
    const int qw = blockIdx.x * 128 + wave * 16;

    const char* qh = (const char*)(ws + OFF_QB + ((size_t)(b*NHEAD + h)) * SEQ * HDIM);
    const char* kh = (const char*)(ws + OFF_KB + ((size_t)(b*NHEAD + h)) * SEQ * HDIM);
    const char* vh = (const char*)(ws + OFF_VT + ((size_t)(b*NHEAD + h)) * SEQ * HDIM);

    __shared__ __align__(16) char Ks[2][2][8192]; // [dbuf][64-key half][perm key][d]
    __shared__ __align__(16) char Vs[2][2][8192]; // [dbuf][64-key half][d][key]

    const unsigned int chunkflags = msum[(b << 4) | blockIdx.x];

    // staging: 512 threads x 16B = one 8KB half-buffer per call; LDS row =
    // tid>>3, phys group tid&7 holds logical group ((tid&7)-row)&7 (rotate).
    // K source row is the PERMUTED key a(row): bits [r5][r3 r2][r4][r1 r0].
    const int srow = tid >> 3;
    const int sgrp = ((tid & 7) - srow) & 7;
    const int arow = (srow & 0x23) | ((srow & 0x0C) << 1) | ((srow & 0x10) >> 2);

    #define STAGE(bfi, k0)                                                           \
        do {                                                                         \
            gl_lds16(kh + (size_t)((k0) + arow) * 128 + sgrp * 16,                   \
                     Ks[bfi][0] + wave * 1024);                                      \
            gl_lds16(kh + (size_t)((k0) + 64 + arow) * 128 + sgrp * 16,              \
                     Ks[bfi][1] + wave * 1024);                                      \
            gl_lds16(vh + (size_t)srow * 4096 + (size_t)(k0) * 2 + sgrp * 16,        \
                     Vs[bfi][0] + wave * 1024);                                      \
            gl_lds16(vh + (size_t)srow * 4096 + (size_t)((k0) + 64) * 2 + sgrp * 16, \
                     Vs[bfi][1] + wave * 1024);                                      \
        } while (0)

    s16x8 qa[2];
    #pragma unroll
    for (int ks = 0; ks < 2; ks++)
        qa[ks] = *(const s16x8*)(qh + (size_t)(qw + l15) * 128 + ks*64 + quad*16);

    // fragment base byte-offsets: rows step by 16 (= 0 mod 8) so the
    // rotation group ((ks*4+quad+row)&7) depends only on (quad+l15);
    // kt/nt contribute pure +2048 immediates.
    const int fbaseA = l15*128 + ((    quad + l15) & 7) * 16;   // ks=0
    const int fbaseB = l15*128 + ((4 + quad + l15) & 7) * 16;   // ks=1

    s16x8 onesf;
    {
        short so = (short)0x3F80;  // bf16 1.0
        if (l15 == 0) onesf = (s16x8){so, so, so, so, so, so, so, so};
        else          onesf = (s16x8){0, 0, 0, 0, 0, 0, 0, 0};
    }

    f32x4 o[4], lsum = {0.f, 0.f, 0.f, 0.f};
    #pragma unroll
    for (int nt = 0; nt < 4; nt++) o[nt] = (f32x4){0.f, 0.f, 0.f, 0.f};

    STAGE(0, 0);
    int bf = 0;
    for (int k0 = 0; k0 < SEQ; k0 += 128) {
        __syncthreads();            // vmcnt(0): buf[bf] staged, buf[bf^1] free
        // prefetch next mega-chunk into the other buffer
        if (k0 + 128 < SEQ) STAGE(bf ^ 1, k0 + 128);

        #pragma unroll
        for (int half = 0; half < 2; half++) {
            const char* Kb = Ks[bf][half];
            const char* Vb = Vs[bf][half];
            const int kc = (k0 >> 6) + half;   // 64-key chunk index 0..31
            // --- S^T = K Q^T (exp2-domain, pre-scaled), K as A-operand from
            //     permuted LDS rows; st[kt][reg] = S[key a(kt*16+quad*4+reg)][q=l15]
            f32x4 st[4];
            #pragma unroll
            for (int kt = 0; kt < 4; kt++) {
                s16x8 kf0 = *(const s16x8*)(Kb + fbaseA + kt*2048);
                s16x8 kf1 = *(const s16x8*)(Kb + fbaseB + kt*2048);
                f32x4 z = {0.f, 0.f, 0.f, 0.f};
                st[kt] = __builtin_amdgcn_mfma_f32_16x16x32_bf16(kf0, qa[0], z, 0, 0, 0);
                st[kt] = __builtin_amdgcn_mfma_f32_16x16x32_bf16(kf1, qa[1], st[kt], 0, 0, 0);
            }
            // --- mask: one u64 per lane (q = qw+l15), bit = PERMUTED key index ---
            if (chunkflags & (1u << kc)) {
                unsigned long long cm =
                    cmask[((size_t)b*32 + kc) * SEQ + qw + l15];
                if (cm != ~0ull) {
                    #pragma unroll
                    for (int kt = 0; kt < 4; kt++)
                        #pragma unroll
                        for (int reg = 0; reg < 4; reg++) {
                            int key = (kt >> 1)*32 + quad*8 + (kt & 1)*4 + reg;
                            if (!((cm >> key) & 1)) st[kt][reg] = -1e9f;
                        }
                }
            }
            // --- P = exp2(S), packed to bf16 via v_perm_b32 (byte-extract =
            //     trunc); lane holds keys ks*32+quad*8..+7 = PV A-octets.
            //     l accumulated on the matrix pipe via ones-column MFMA ---
            #pragma unroll
            for (int ks = 0; ks < 2; ks++) {
                unsigned int pb[8];
                #pragma unroll
                for (int j = 0; j < 8; j++) {
                    int kt = 2*ks + (j >> 2), r = j & 3;
                    pb[j] = __builtin_bit_cast(unsigned int, exp2f(st[kt][r]));
                }
                u32x4 pw;
                pw[0] = __builtin_amdgcn_perm(pb[1], pb[0], 0x07060302u);
                pw[1] = __builtin_amdgcn_perm(pb[3], pb[2], 0x07060302u);
                pw[2] = __builtin_amdgcn_perm(pb[5], pb[4], 0x07060302u);
                pw[3] = __builtin_amdgcn_perm(pb[7], pb[6], 0x07060302u);
                s16x8 pa = __builtin_bit_cast(s16x8, pw);
                lsum = __builtin_amdgcn_mfma_f32_16x16x32_bf16(pa, onesf, lsum, 0, 0, 0);
                const int fb = (ks == 0) ? fbaseA : fbaseB;
                #pragma unroll
                for (int nt = 0; nt < 4; nt++) {
                    s16x8 vf = *(const s16x8*)(Vb + fb + nt*2048);
                    o[nt] = __builtin_amdgcn_mfma_f32_16x16x32_bf16(pa, vf, o[nt], 0, 0, 0);
                }
            }
        }
        bf ^= 1;
    }
    #undef STAGE
    // --- epilogue: O / l -> ab [B,S,DMODEL] bf16.
    //     O and lsum share the C layout: row q = quad*4+reg, col = l15
    //     (l valid at col 0 -> lane quad*16 = lane&48) ---
    #pragma unroll
    for (int reg = 0; reg < 4; reg++) {
        float lv = __shfl(lsum[reg], lane & 48);
        float inv = 1.f / lv;
        int sg = qw + quad*4 + reg;
        #pragma unroll
        for (int nt = 0; nt < 4; nt++) {
            size_t idx = ((size_t)b * SEQ + sg) * DMODEL + h*HDIM + nt*16 + l15;
            ab[idx] = f2bf(o[nt][reg] * inv);
        }
    }
}

// ---------------------------------------------------------------------------
// LayerNorm (unbiased std, (std+eps) denominator), in-place on fp32 rows
// ---------------------------------------------------------------------------
__global__ __launch_bounds__(256) void ln_kernel(
    float* __restrict__ x, const float* __restrict__ gamma,
    const float* __restrict__ beta)
{
    const int row = blockIdx.x;
    const int tid = threadIdx.x;
    float4 vals = *(const float4*)&x[(size_t)row * DMODEL + tid * 4];
    float s  = vals.x + vals.y + vals.z + vals.w;
    float ss = vals.x*vals.x + vals.y*vals.y + vals.z*vals.z + vals.w*vals.w;
    #pragma unroll
    for (int off = 32; off > 0; off >>= 1) {
        s  += __shfl_down(s, off);
        ss += __shfl_down(ss, off);
    }
    __shared__ float sbuf[4], ssbuf[4];
    __shared__ float mean_s, inv_s;
    if ((tid & 63) == 0) { sbuf[tid >> 6] = s; ssbuf[tid >> 6] = ss; }
    __syncthreads();
    if (tid == 0) {
        float S1 = 0.f, S2 = 0.f;
        #pragma unroll
        for (int i = 0; i < 4; i++) { S1 += sbuf[i]; S2 += ssbuf[i]; }
        float mean = S1 * (1.0f / DMODEL);
        float var  = (S2 - (float)DMODEL * mean * mean) * (1.0f / (DMODEL - 1));
        float sd   = sqrtf(fmaxf(var, 0.f));
        mean_s = mean;
        inv_s  = 1.f / (sd + EPS);
    }
    __syncthreads();
    float4 g  = *(const float4*)&gamma[tid * 4];
    float4 bt = *(const float4*)&beta[tid * 4];
    float4 o;
    o.x = g.x * (vals.x - mean_s) * inv_s + bt.x;
    o.y = g.y * (vals.y - mean_s) * inv_s + bt.y;
    o.z = g.z * (vals.z - mean_s) * inv_s + bt.z;
    o.w = g.w * (vals.w - mean_s) * inv_s + bt.w;
    *(float4*)&x[(size_t)row * DMODEL + tid * 4] = o;
}

extern "C" void kernel_launch(void* const* d_in, const int* in_sizes, int n_in,
                              void* d_out, int out_size, void* d_ws, size_t ws_size,
                              hipStream_t stream) {
    const float* query = (const float*)d_in[0];
    const float* key   = (const float*)d_in[1];
    const float* value = (const float*)d_in[2];
    const int*   mask  = (const int*)d_in[3];
    const float* Wq = (const float*)d_in[4];  const float* bq = (const float*)d_in[5];
    const float* Wk = (const float*)d_in[6];  const float* bk = (const float*)d_in[7];
    const float* Wv = (const float*)d_in[8];  const float* bv = (const float*)d_in[9];
    const float* Wo = (const float*)d_in[10]; const float* bo = (const float*)d_in[11];
    const float* gamma = (const float*)d_in[12];
    const float* beta  = (const float*)d_in[13];
    float* out = (float*)d_out;

    unsigned short* ws = (unsigned short*)d_ws;
    unsigned long long* cmask = (unsigned long long*)(ws + OFF_CM);
    unsigned int* msum = (unsigned int*)(ws + OFF_MS);

    conv_all_kernel<<<16384, 256, 0, stream>>>(query, key, value, Wq, Wk, Wv, Wo, ws);
    mask_compress_kernel<<<2048, 256, 0, stream>>>(mask, cmask, msum);
    qkv_gemm_kernel<<<dim3(32, 8, 3), 256, 0, stream>>>(ws, bq, bk, bv);
    attn_mfma_kernel<<<dim3(SEQ/128, NHEAD, BATCH), 512, 0, stream>>>(ws, cmask, msum, ws + OFF_XQ);
    oproj_gemm_kernel<<<dim3(32, 8), 256, 0, stream>>>(ws, bo, query, out);
    ln_kernel<<<NROWS, 256, 0, stream>>>(out, gamma, beta);
}

// Round 12
// 267.520 us; speedup vs baseline: 1.1971x; 1.0186x over previous
//
#include <hip/hip_runtime.h>
#include <hip/hip_bf16.h>
#include <math.h>
#include <stdint.h>

#define BATCH 2
#define SEQ   2048
#define DMODEL 1024
#define NHEAD 16
#define HDIM  64
#define NROWS (BATCH*SEQ)          // 4096
#define EPS   1e-6f
#define QSCALE 0.1803368801111204f // 0.125 * log2(e): softmax in exp2 domain

typedef float f32x4 __attribute__((ext_vector_type(4)));
typedef short s16x8 __attribute__((ext_vector_type(8)));
typedef unsigned int u32x4 __attribute__((ext_vector_type(4)));

// ws layout (ushort units):
//  xq @ 0            (4194304)   -> reused as ab (attention out) after projections
//  xk @ 4194304
//  xv @ 8388608
//  wq @ 12582912     (1048576 each)
//  wk @ 13631488
//  wv @ 14680064
//  wo @ 15728640
//  qb @ 16777216     [B,H,S,64] bf16, pre-scaled by QSCALE
//  kb @ 20971520     [B,H,S,64] bf16
//  vt @ 25165824     [B,H,64,S] bf16 (V transposed)
//  cmask @ 29360128  (1 MB): [B][32 kblocks][S] uint64 bitmask
//  msum  @ 29884416  (128 B): [B][16 qb128] uint32, bit kb = "has masked"
#define OFF_XQ 0
#define OFF_XK 4194304
#define OFF_XV 8388608
#define OFF_WQ 12582912
#define OFF_WK 13631488
#define OFF_WV 14680064
#define OFF_WO 15728640
#define OFF_QB 16777216
#define OFF_KB 20971520
#define OFF_VT 25165824
#define OFF_CM 29360128
#define OFF_MS 29884416

__device__ __forceinline__ unsigned short f2bf(float x) {
    unsigned int u = __builtin_bit_cast(unsigned int, x);
    u += 0x7fff + ((u >> 16) & 1);            // round-to-nearest-even
    return (unsigned short)(u >> 16);
}

__device__ __forceinline__ void gl_lds16(const void* g, void* l) {
    __builtin_amdgcn_global_load_lds(
        (const __attribute__((address_space(1))) unsigned int*)g,
        (__attribute__((address_space(3))) unsigned int*)(unsigned int)(unsigned long long)l,
        16, 0, 0);
}

// ---------------------------------------------------------------------------
// fused fp32 -> bf16 convert of query/key/value + 4 weight matrices
// (also zero-inits the mask summary words for the following dispatch).
// R20: grid-stride 2048 blocks x 8 iters (was 16384 tiny blocks -- G11:
// cap grid, stride the rest; trims block-dispatch tail on a BW-bound pass).
// ---------------------------------------------------------------------------
__global__ __launch_bounds__(256) void conv_all_kernel(
    const float* __restrict__ q, const float* __restrict__ k, const float* __restrict__ v,
    const float* __restrict__ wq, const float* __restrict__ wk, const float* __restrict__ wv,
    const float* __restrict__ wo, unsigned short* __restrict__ ws)
{
    if (blockIdx.x == 0 && threadIdx.x < 32)
        ((unsigned int*)(ws + OFF_MS))[threadIdx.x] = 0;
    #pragma unroll
    for (int it = 0; it < 8; it++) {
        size_t t = (((size_t)it * 2048 + blockIdx.x) * 256 + threadIdx.x) * 4;
        const float* src; unsigned short* dst; size_t off;
        if (t < 4194304)       { src = q;  dst = ws + OFF_XQ; off = t; }
        else if (t < 8388608)  { src = k;  dst = ws + OFF_XK; off = t - 4194304; }
        else if (t < 12582912) { src = v;  dst = ws + OFF_XV; off = t - 8388608; }
        else if (t < 13631488) { src = wq; dst = ws + OFF_WQ; off = t - 12582912; }
        else if (t < 14680064) { src = wk; dst = ws + OFF_WK; off = t - 13631488; }
        else if (t < 15728640) { src = wv; dst = ws + OFF_WV; off = t - 14680064; }
        else                   { src = wo; dst = ws + OFF_WO; off = t - 15728640; }
        float4 x = *(const float4*)&src[off];
        ushort4 o;
        o.x = f2bf(x.x); o.y = f2bf(x.y); o.z = f2bf(x.z); o.w = f2bf(x.w);
        *(ushort4*)&dst[off] = o;
    }
}

// ---------------------------------------------------------------------------
// mask -> per-(b, kblock, s) 64-bit bitmask + per-(b, qb128) chunk summary.
// One wave per row, grid-strided x16 over 2048 blocks: lane reads
// mask[b][s][kb*64+lane] (coalesced 256B/wave), __ballot assembles the
// 64-bit mask in one instruction. Kept as a SEPARATE kernel: fusing into a
// compute dispatch made the serial ballot loop the long pole (R18, +44us),
// and fusing into conv would race block-0's msum zero-init (G16).
// ---------------------------------------------------------------------------
__global__ __launch_bounds__(256) void mask_compress_kernel(
    const int* __restrict__ mask, unsigned long long* __restrict__ cm,
    unsigned int* __restrict__ msum)
{
    const int lane = threadIdx.x & 63;
    const int wid = (blockIdx.x * 256 + threadIdx.x) >> 6;   // [0, 8192)
    #pragma unroll
    for (int i = 0; i < 16; i++) {
        int w = wid + i * 8192;              // row id [0, 131072)
        int s  = w & 2047;
        int kb = (w >> 11) & 31;
        int b  = w >> 16;
        int m = mask[((size_t)b * SEQ + s) * SEQ + kb * 64 + lane];
        unsigned long long bits = __ballot(m != 0);
        if (lane == 0) {
            cm[((size_t)b * 32 + kb) * SEQ + s] = bits;
            if (bits != ~0ull)
                atomicOr(&msum[(b << 4) | (s >> 7)], 1u << kb);
        }
    }
}

// ---------------------------------------------------------------------------
// GEMM tile bodies: C[128x128] += A[r0..] * W[c0..]^T, bf16 MFMA.
// A,W row-major bf16 with K stride 1024. Per-wave 64x64 = 4x4 C-frags.
// LDS rows XOR-ROTATED by row index (rotation folded into the GLOBAL source
// address); fragment rows step by 16 (= 0 mod 8) so the rotation group is
// independent of mt/nt -> hoisted base offsets.
// TWO variants (R20):
//  * _sb: single-buffer 32KB (stage->barrier->compute). For qkv: grid =
//    3 blocks/CU, co-resident blocks hide the stage drain (m114); 32KB
//    keeps 3 blocks/CU (R19's 64KB dbuf silently halved it to 2).
//  * _db: double-buffered 64KB (attn's STAGE-ahead). For oproj: grid =
//    256 = 1 block/CU -- no co-resident overlap, dbuf is the only
//    latency-hiding; 64KB costs nothing at 1 block/CU.
// ---------------------------------------------------------------------------
__device__ __forceinline__ void gemm_body_sb(
    const unsigned short* A, const unsigned short* W, int r0, int c0,
    unsigned short* As, unsigned short* Bs, f32x4 acc[4][4])
{
    const int tid  = threadIdx.x;
    const int wave = tid >> 6, lane = tid & 63;
    const int quad = lane >> 4, l15 = lane & 15;
    const int wr = wave >> 1, wc = wave & 1;
    const int aBase0 = (wr*64 + l15)*128 + ((    quad + l15) & 7)*16;
    const int aBase1 = (wr*64 + l15)*128 + ((4 + quad + l15) & 7)*16;
    const int bBase0 = (wc*64 + l15)*128 + ((    quad + l15) & 7)*16;
    const int bBase1 = (wc*64 + l15)*128 + ((4 + quad + l15) & 7)*16;
    for (int k0 = 0; k0 < DMODEL; k0 += 64) {
        __syncthreads();
        #pragma unroll
        for (int r = 0; r < 4; r++) {
            int f   = r * 4096 + tid * 16;    // byte offset in 16KB tile
            int row = f >> 7;                 // tile row 0..127
            int g   = (((f >> 4) & 7) - row) & 7;   // logical group at this slot
            gl_lds16((const char*)A + (size_t)(r0 + row) * 2048 + k0 * 2 + g * 16,
                     (char*)As + r * 4096 + wave * 1024);
            gl_lds16((const char*)W + (size_t)(c0 + row) * 2048 + k0 * 2 + g * 16,
                     (char*)Bs + r * 4096 + wave * 1024);
        }
        __syncthreads();
        #pragma unroll
        for (int ks = 0; ks < 2; ks++) {
            const int aB = ks ? aBase1 : aBase0;
            const int bB = ks ? bBase1 : bBase0;
            s16x8 a[4], b[4];
            #pragma unroll
            for (int mt = 0; mt < 4; mt++)
                a[mt] = *(const s16x8*)((const char*)As + aB + mt*2048);
            #pragma unroll
            for (int nt = 0; nt < 4; nt++)
                b[nt] = *(const s16x8*)((const char*)Bs + bB + nt*2048);
            #pragma unroll
            for (int mt = 0; mt < 4; mt++)
                #pragma unroll
                for (int nt = 0; nt < 4; nt++)
                    acc[mt][nt] = __builtin_amdgcn_mfma_f32_16x16x32_bf16(a[mt], b[nt], acc[mt][nt], 0, 0, 0);
        }
    }
}

__device__ __forceinline__ void gemm_body_db(
    const unsigned short* A, const unsigned short* W, int r0, int c0,
    unsigned short (*As)[8192], unsigned short (*Bs)[8192], f32x4 acc[4][4])
{
    const int tid  = threadIdx.x;
    const int wave = tid >> 6, lane = tid & 63;
    const int quad = lane >> 4, l15 = lane & 15;
    const int wr = wave >> 1, wc = wave & 1;
    const int aBase0 = (wr*64 + l15)*128 + ((    quad + l15) & 7)*16;
    const int aBase1 = (wr*64 + l15)*128 + ((4 + quad + l15) & 7)*16;
    const int bBase0 = (wc*64 + l15)*128 + ((    quad + l15) & 7)*16;
    const int bBase1 = (wc*64 + l15)*128 + ((4 + quad + l15) & 7)*16;

    #define GSTAGE(bfi, k0)                                                            \
        do {                                                                           \
            _Pragma("unroll")                                                          \
            for (int r = 0; r < 4; r++) {                                              \
                int f   = r * 4096 + tid * 16;                                         \
                int row = f >> 7;                                                      \
                int g   = (((f >> 4) & 7) - row) & 7;                                  \
                gl_lds16((const char*)A + (size_t)(r0 + row) * 2048 + (k0) * 2 + g * 16, \
                         (char*)As[bfi] + r * 4096 + wave * 1024);                     \
                gl_lds16((const char*)W + (size_t)(c0 + row) * 2048 + (k0) * 2 + g * 16, \
                         (char*)Bs[bfi] + r * 4096 + wave * 1024);                     \
            }                                                                          \
        } while (0)

    GSTAGE(0, 0);
    int bf = 0;
    for (int k0 = 0; k0 < DMODEL; k0 += 64) {
        __syncthreads();              // vmcnt(0): buf[bf] staged, buf[bf^1] free
        if (k0 + 64 < DMODEL) GSTAGE(bf ^ 1, k0 + 64);
        #pragma unroll
        for (int ks = 0; ks < 2; ks++) {
            const int aB = ks ? aBase1 : aBase0;
            const int bB = ks ? bBase1 : bBase0;
            s16x8 a[4], b[4];
            #pragma unroll
            for (int mt = 0; mt < 4; mt++)
                a[mt] = *(const s16x8*)((const char*)As[bf] + aB + mt*2048);
            #pragma unroll
            for (int nt = 0; nt < 4; nt++)
                b[nt] = *(const s16x8*)((const char*)Bs[bf] + bB + nt*2048);
            #pragma unroll
            for (int mt = 0; mt < 4; mt++)
                #pragma unroll
                for (int nt = 0; nt < 4; nt++)
                    acc[mt][nt] = __builtin_amdgcn_mfma_f32_16x16x32_bf16(a[mt], b[nt], acc[mt][nt], 0, 0, 0);
        }
        bf ^= 1;
    }
    #undef GSTAGE
}

// ---------------------------------------------------------------------------
// QKV projections: z=0 -> q (scaled, [B,H,S,d]), z=1 -> k ([B,H,S,d]),
// z=2 -> V^T computed DIRECTLY as Wv * X^T (operand swap, coalesced stores).
// Single-buffer gemm body: 32KB LDS -> 3 blocks/CU co-residency.
// ---------------------------------------------------------------------------
__global__ __launch_bounds__(256) void qkv_gemm_kernel(
    unsigned short* __restrict__ ws,
    const float* __restrict__ bq, const float* __restrict__ bk, const float* __restrict__ bv)
{
    __shared__ __align__(16) unsigned short As[8192];
    __shared__ __align__(16) unsigned short Bs[8192];
    const int z = blockIdx.z;
    const unsigned short *A, *W;
    int r0, c0;
    if (z != 2) {
        A = ws + (size_t)z * 4194304;            // xq/xk
        W = ws + OFF_WQ + (size_t)z * 1048576;
        r0 = blockIdx.x * 128; c0 = blockIdx.y * 128;
    } else {
        A = ws + OFF_WV;                         // rows = output features
        W = ws + OFF_XV;                         // "cols" = seq rows
        r0 = blockIdx.y * 128; c0 = blockIdx.x * 128;
    }
    const float* bias = (z == 0) ? bq : (z == 1 ? bk : bv);
    unsigned short* outp = ws + OFF_QB + (size_t)z * 4194304;      // qb/kb/vt
    const float scale = (z == 0) ? QSCALE : 1.0f;

    f32x4 acc[4][4] = {};
    gemm_body_sb(A, W, r0, c0, As, Bs, acc);

    const int lane = threadIdx.x & 63, wave = threadIdx.x >> 6;
    const int quad = lane >> 4, l15 = lane & 15;
    const int wr = wave >> 1, wc = wave & 1;
    if (z != 2) {
        float bias_v[4];
        #pragma unroll
        for (int nt = 0; nt < 4; nt++) bias_v[nt] = bias[c0 + wc*64 + nt*16 + l15];
        #pragma unroll
        for (int mt = 0; mt < 4; mt++) {
            #pragma unroll
            for (int nt = 0; nt < 4; nt++) {
                int c = c0 + wc*64 + nt*16 + l15;
                int hh = c >> 6, dd = c & 63;
                #pragma unroll
                for (int reg = 0; reg < 4; reg++) {
                    int r = r0 + wr*64 + mt*16 + quad*4 + reg;
                    int bb = r >> 11, ss = r & (SEQ - 1);
                    float val = (acc[mt][nt][reg] + bias_v[nt]) * scale;
                    outp[(((size_t)(bb*NHEAD + hh)) * SEQ + ss) * HDIM + dd] = f2bf(val);
                }
            }
        }
    } else {
        #pragma unroll
        for (int mt = 0; mt < 4; mt++) {
            #pragma unroll
            for (int reg = 0; reg < 4; reg++) {
                int f = r0 + wr*64 + mt*16 + quad*4 + reg;   // feature
                int hh = f >> 6, dd = f & 63;
                float bfv = bias[f];
                #pragma unroll
                for (int nt = 0; nt < 4; nt++) {
                    int r = c0 + wc*64 + nt*16 + l15;        // seq row
                    int bb = r >> 11, ss = r & (SEQ - 1);
                    outp[(((size_t)(bb*NHEAD + hh)) * HDIM + dd) * SEQ + ss] =
                        f2bf(acc[mt][nt][reg] + bfv);
                }
            }
        }
    }
}

// ---------------------------------------------------------------------------
// Out projection: out = ab @ Wo^T + bo + residual  (fp32 out).
// Double-buffered gemm body: grid = 256 = 1 block/CU, so dbuf is the only
// available latency hiding and the 64KB LDS is free.
// ---------------------------------------------------------------------------
__global__ __launch_bounds__(256) void oproj_gemm_kernel(
    const unsigned short* __restrict__ ws, const float* __restrict__ bo,
    const float* __restrict__ resid, float* __restrict__ outf)
{
    __shared__ __align__(16) unsigned short As[2][8192];
    __shared__ __align__(16) unsigned short Bs[2][8192];
    const unsigned short* A = ws + OFF_XQ;      // ab lives where xq was
    const unsigned short* W = ws + OFF_WO;
    const int r0 = blockIdx.x * 128, c0 = blockIdx.y * 128;

    f32x4 acc[4][4] = {};
    gemm_body_db(A, W, r0, c0, As, Bs, acc);

    const int lane = threadIdx.x & 63, wave = threadIdx.x >> 6;
    const int quad = lane >> 4, l15 = lane & 15;
    const int wr = wave >> 1, wc = wave & 1;
    #pragma unroll
    for (int mt = 0; mt < 4; mt++) {
        #pragma unroll
        for (int nt = 0; nt < 4; nt++) {
            int c = c0 + wc*64 + nt*16 + l15;
            float bv = bo[c];
            #pragma unroll
            for (int reg = 0; reg < 4; reg++) {
                int r = r0 + wr*64 + mt*16 + quad*4 + reg;
                size_t idx = (size_t)r * DMODEL + c;
                outf[idx] = acc[mt][nt][reg] + bv + resid[idx];
            }
        }
    }
}

// ---------------------------------------------------------------------------
// Flash attention, bf16 MFMA, static softmax. The proven R14 structure
// (best measured: 57.6us): 512 thr, 8 waves x 16 q-rows, swapped QK^T,
// key-permuted K staging, P in registers via v_perm_b32, l via ones-column
// MFMA, 128-key mega-chunks (two 8KB half-buffers per operand per dbuf
// slot, one barrier per 128 keys), 0 bank conflicts, fbase offset hoist.
// FROZEN: R15 stagger (neutral), R16/R17 key-split (worse), R9 32-row
// waves (occupancy loss), R10 reg-K (compiler sinks prefetch) all falsified.
// ---------------------------------------------------------------------------
__global__ __launch_bounds__(512) void attn_mfma_kernel(
    const unsigned short* __restrict__ ws,
    const unsigned long long* __restrict__ cmask,
    const unsigned int* __restrict__ msum,
    unsigned short* __restrict__ ab)
{
    const int tid  = threadIdx.x;
    const int wave = tid >> 6, lane = tid & 63;
    const int quad = lane >> 4, l15 = lane & 15;
    const int h = blockIdx.y, b = blockIdx.z;
    const int qw = blockIdx.x * 128 + wave * 16;

    const char* qh = (const char*)(ws + OFF_QB + ((size_t)(b*NHEAD + h)) * SEQ * HDIM);
    const char* kh = (const char*)(ws + OFF_KB + ((size_t)(b*NHEAD + h)) * SEQ * HDIM);
    const char* vh = (const char*)(ws + OFF_VT + ((size_t)(b*NHEAD + h)) * SEQ * HDIM);

    __shared__ __align__(16) char Ks[2][2][8192]; // [dbuf][64-key half][perm key][d]
    __shared__ __align__(16) char Vs[2][2][8192]; // [dbuf][64-key half][d][key]

    const unsigned int chunkflags = msum[(b << 4) | blockIdx.x];

    // staging: 512 threads x 16B = one 8KB half-buffer per call; LDS row =
    // tid>>3, phys group tid&7 holds logical group ((tid&7)-row)&7 (rotate).
    // K source row is the PERMUTED key a(row): bits [r5][r3 r2][r4][r1 r0].
    const int srow = tid >> 3;
    const int sgrp = ((tid & 7) - srow) & 7;
    const int arow = (srow & 0x23) | ((srow & 0x0C) << 1) | ((srow & 0x10) >> 2);

    #define STAGE(bfi, k0)                                                           \
        do {                                                                         \
            gl_lds16(kh + (size_t)((k0) + arow) * 128 + sgrp * 16,                   \
                     Ks[bfi][0] + wave * 1024);                                      \
            gl_lds16(kh + (size_t)((k0) + 64 + arow) * 128 + sgrp * 16,              \
                     Ks[bfi][1] + wave * 1024);                                      \
            gl_lds16(vh + (size_t)srow * 4096 + (size_t)(k0) * 2 + sgrp * 16,        \
                     Vs[bfi][0] + wave * 1024);                                      \
            gl_lds16(vh + (size_t)srow * 4096 + (size_t)((k0) + 64) * 2 + sgrp * 16, \
                     Vs[bfi][1] + wave * 1024);                                      \
        } while (0)

    s16x8 qa[2];
    #pragma unroll
    for (int ks = 0; ks < 2; ks++)
        qa[ks] = *(const s16x8*)(qh + (size_t)(qw + l15) * 128 + ks*64 + quad*16);

    // fragment base byte-offsets: rows step by 16 (= 0 mod 8) so the
    // rotation group ((ks*4+quad+row)&7) depends only on (quad+l15);
    // kt/nt contribute pure +2048 immediates.
    const int fbaseA = l15*128 + ((    quad + l15) & 7) * 16;   // ks=0
    const int fbaseB = l15*128 + ((4 + quad + l15) & 7) * 16;   // ks=1

    s16x8 onesf;
    {
        short so = (short)0x3F80;  // bf16 1.0
        if (l15 == 0) onesf = (s16x8){so, so, so, so, so, so, so, so};
        else          onesf = (s16x8){0, 0, 0, 0, 0, 0, 0, 0};
    }

    f32x4 o[4], lsum = {0.f, 0.f, 0.f, 0.f};
    #pragma unroll
    for (int nt = 0; nt < 4; nt++) o[nt] = (f32x4){0.f, 0.f, 0.f, 0.f};

    STAGE(0, 0);
    int bf = 0;
    for (int k0 = 0; k0 < SEQ; k0 += 128) {
        __syncthreads();            // vmcnt(0): buf[bf] staged, buf[bf^1] free
        // prefetch next mega-chunk into the other buffer
        if (k0 + 128 < SEQ) STAGE(bf ^ 1, k0 + 128);

        #pragma unroll
        for (int half = 0; half < 2; half++) {
            const char* Kb = Ks[bf][half];
            const char* Vb = Vs[bf][half];
            const int kc = (k0 >> 6) + half;   // 64-key chunk index 0..31
            // --- S^T = K Q^T (exp2-domain, pre-scaled), K as A-operand from
            //     permuted LDS rows; st[kt][reg] = S[key a(kt*16+quad*4+reg)][q=l15]
            f32x4 st[4];
            #pragma unroll
            for (int kt = 0; kt < 4; kt++) {
                s16x8 kf0 = *(const s16x8*)(Kb + fbaseA + kt*2048);
                s16x8 kf1 = *(const s16x8*)(Kb + fbaseB + kt*2048);
                f32x4 z = {0.f, 0.f, 0.f, 0.f};
                st[kt] = __builtin_amdgcn_mfma_f32_16x16x32_bf16(kf0, qa[0], z, 0, 0, 0);
                st[kt] = __builtin_amdgcn_mfma_f32_16x16x32_bf16(kf1, qa[1], st[kt], 0, 0, 0);
            }
            // --- mask: one u64 per lane (q = qw+l15), bit = PERMUTED key index ---
            if (chunkflags & (1u << kc)) {
                unsigned long long cm =
                    cmask[((size_t)b*32 + kc) * SEQ + qw + l15];
                if (cm != ~0ull) {
                    #pragma unroll
                    for (int kt = 0; kt < 4; kt++)
                        #pragma unroll
                        for (int reg = 0; reg < 4; reg++) {
                            int key = (kt >> 1)*32 + quad*8 + (kt & 1)*4 + reg;
                            if (!((cm >> key) & 1)) st[kt][reg] = -1e9f;
                        }
                }
            }
            // --- P = exp2(S), packed to bf16 via v_perm_b32 (byte-extract =
            //     trunc); lane holds keys ks*32+quad*8..+7 = PV A-octets.
            //     l accumulated on the matrix pipe via ones-column MFMA ---
            #pragma unroll
            for (int ks = 0; ks < 2; ks++) {
                unsigned int pb[8];
                #pragma unroll
                for (int j = 0; j < 8; j++) {
                    int kt = 2*ks + (j >> 2), r = j & 3;
                    pb[j] = __builtin_bit_cast(unsigned int, exp2f(st[kt][r]));
                }
                u32x4 pw;
                pw[0] = __builtin_amdgcn_perm(pb[1], pb[0], 0x07060302u);
                pw[1] = __builtin_amdgcn_perm(pb[3], pb[2], 0x07060302u);
                pw[2] = __builtin_amdgcn_perm(pb[5], pb[4], 0x07060302u);
                pw[3] = __builtin_amdgcn_perm(pb[7], pb[6], 0x07060302u);
                s16x8 pa = __builtin_bit_cast(s16x8, pw);
                lsum = __builtin_amdgcn_mfma_f32_16x16x32_bf16(pa, onesf, lsum, 0, 0, 0);
                const int fb = (ks == 0) ? fbaseA : fbaseB;
                #pragma unroll
                for (int nt = 0; nt < 4; nt++) {
                    s16x8 vf = *(const s16x8*)(Vb + fb + nt*2048);
                    o[nt] = __builtin_amdgcn_mfma_f32_16x16x32_bf16(pa, vf, o[nt], 0, 0, 0);
                }
            }
        }
        bf ^= 1;
    }
    #undef STAGE
    // --- epilogue: O / l -> ab [B,S,DMODEL] bf16.
    //     O and lsum share the C layout: row q = quad*4+reg, col = l15
    //     (l valid at col 0 -> lane quad*16 = lane&48) ---
    #pragma unroll
    for (int reg = 0; reg < 4; reg++) {
        float lv = __shfl(lsum[reg], lane & 48);
        float inv = 1.f / lv;
        int sg = qw + quad*4 + reg;
        #pragma unroll
        for (int nt = 0; nt < 4; nt++) {
            size_t idx = ((size_t)b * SEQ + sg) * DMODEL + h*HDIM + nt*16 + l15;
            ab[idx] = f2bf(o[nt][reg] * inv);
        }
    }
}

// ---------------------------------------------------------------------------
// LayerNorm (unbiased std, (std+eps) denominator), in-place on fp32 rows
// ---------------------------------------------------------------------------
__global__ __launch_bounds__(256) void ln_kernel(
    float* __restrict__ x, const float* __restrict__ gamma,
    const float* __restrict__ beta)
{
    const int row = blockIdx.x;
    const int tid = threadIdx.x;
    float4 vals = *(const float4*)&x[(size_t)row * DMODEL + tid * 4];
    float s  = vals.x + vals.y + vals.z + vals.w;
    float ss = vals.x*vals.x + vals.y*vals.y + vals.z*vals.z + vals.w*vals.w;
    #pragma unroll
    for (int off = 32; off > 0; off >>= 1) {
        s  += __shfl_down(s, off);
        ss += __shfl_down(ss, off);
    }
    __shared__ float sbuf[4], ssbuf[4];
    __shared__ float mean_s, inv_s;
    if ((tid & 63) == 0) { sbuf[tid >> 6] = s; ssbuf[tid >> 6] = ss; }
    __syncthreads();
    if (tid == 0) {
        float S1 = 0.f, S2 = 0.f;
        #pragma unroll
        for (int i = 0; i < 4; i++) { S1 += sbuf[i]; S2 += ssbuf[i]; }
        float mean = S1 * (1.0f / DMODEL);
        float var  = (S2 - (float)DMODEL * mean * mean) * (1.0f / (DMODEL - 1));
        float sd   = sqrtf(fmaxf(var, 0.f));
        mean_s = mean;
        inv_s  = 1.f / (sd + EPS);
    }
    __syncthreads();
    float4 g  = *(const float4*)&gamma[tid * 4];
    float4 bt = *(const float4*)&beta[tid * 4];
    float4 o;
    o.x = g.x * (vals.x - mean_s) * inv_s + bt.x;
    o.y = g.y * (vals.y - mean_s) * inv_s + bt.y;
    o.z = g.z * (vals.z - mean_s) * inv_s + bt.z;
    o.w = g.w * (vals.w - mean_s) * inv_s + bt.w;
    *(float4*)&x[(size_t)row * DMODEL + tid * 4] = o;
}

extern "C" void kernel_launch(void* const* d_in, const int* in_sizes, int n_in,
                              void* d_out, int out_size, void* d_ws, size_t ws_size,
                              hipStream_t stream) {
    const float* query = (const float*)d_in[0];
    const float* key   = (const float*)d_in[1];
    const float* value = (const float*)d_in[2];
    const int*   mask  = (const int*)d_in[3];
    const float* Wq = (const float*)d_in[4];  const float* bq = (const float*)d_in[5];
    const float* Wk = (const float*)d_in[6];  const float* bk = (const float*)d_in[7];
    const float* Wv = (const float*)d_in[8];  const float* bv = (const float*)d_in[9];
    const float* Wo = (const float*)d_in[10]; const float* bo = (const float*)d_in[11];
    const float* gamma = (const float*)d_in[12];
    const float* beta  = (const float*)d_in[13];
    float* out = (float*)d_out;

    unsigned short* ws = (unsigned short*)d_ws;
    unsigned long long* cmask = (unsigned long long*)(ws + OFF_CM);
    unsigned int* msum = (unsigned int*)(ws + OFF_MS);

    conv_all_kernel<<<2048, 256, 0, stream>>>(query, key, value, Wq, Wk, Wv, Wo, ws);
    mask_compress_kernel<<<2048, 256, 0, stream>>>(mask, cmask, msum);
    qkv_gemm_kernel<<<dim3(32, 8, 3), 256, 0, stream>>>(ws, bq, bk, bv);
    attn_mfma_kernel<<<dim3(SEQ/128, NHEAD, BATCH), 512, 0, stream>>>(ws, cmask, msum, ws + OFF_XQ);
    oproj_gemm_kernel<<<dim3(32, 8), 256, 0, stream>>>(ws, bo, query, out);
    ln_kernel<<<NROWS, 256, 0, stream>>>(out, gamma, beta);
}